// Round 9
// baseline (164.750 us; speedup 1.0000x reference)
//
#include <hip/hip_runtime.h>
#include <math.h>

#define N_TOK 4096
#define DIM 256
#define NHEAD 4
#define DPH 64
#define NEXP 9
#define SCALE 0.25f
#define MAXST 80    // 64-row supertiles: <= 64 + 9
#define GPAD 4736   // 64-aligned grouped rows upper bound
#define VPITCH 4736
#define NSPLIT 2    // key-range splits per (supertile, head)

typedef short s8 __attribute__((ext_vector_type(8)));
typedef short s4 __attribute__((ext_vector_type(4)));
typedef float f4 __attribute__((ext_vector_type(4)));

static __device__ __forceinline__ short f2bf(float f) {
  union { float f; unsigned u; } v;
  v.f = f;
  unsigned r = (v.u + 0x7FFFu + ((v.u >> 16) & 1u)) >> 16;
  return (short)r;
}

static __device__ __forceinline__ float wave_sum(float v) {
#pragma unroll
  for (int o = 32; o > 0; o >>= 1) v += __shfl_xor(v, o, 64);
  return v;
}

// ---------------------------------------------------------------------------
// Kernel 1: prep. Block 0: bucket tokens via BALLOT histogram/rank (few LDS
// atomics instead of 8192 same-address ones). Blocks 1..448: W fp32 [d][h] ->
// WbT bf16 [slab][h][d]. Blocks 449..512: x -> bf16 cast. All independent.
// ---------------------------------------------------------------------------
__global__ __launch_bounds__(256) void k_prep(
    const float* __restrict__ x, const int* __restrict__ label,
    const float* __restrict__ Wq, const float* __restrict__ Wk,
    const float* __restrict__ Wv, const float* __restrict__ Wf,
    int* __restrict__ perm, int* __restrict__ iperm, int* __restrict__ gs,
    int* __restrict__ gep, int* __restrict__ st_e, int* __restrict__ st_row,
    int* __restrict__ nstp, short* __restrict__ WbT, short* __restrict__ xb) {
  int b = blockIdx.x;
  int tid = threadIdx.x;
  if (b == 0) {
    __shared__ int cntL[NEXP], baseL[NEXP];
    int wl = tid >> 6, lane = tid & 63;
    if (tid < NEXP) cntL[tid] = 0;
    __syncthreads();
    int lab[16];
#pragma unroll
    for (int i = 0; i < 16; i++) lab[i] = label[(wl * 16 + i) * 64 + lane];
    // Count: one LDS atomic per (wave, chunk, expert) with nonzero count.
#pragma unroll
    for (int i = 0; i < 16; i++) {
#pragma unroll
      for (int e = 0; e < NEXP; e++) {
        unsigned long long mk = __ballot(lab[i] == e);
        int c = __popcll(mk);
        if (c && lane == 0) atomicAdd(&cntL[e], c);
      }
    }
    __syncthreads();
    if (tid == 0) {
      int run = 0, ns = 0;
      for (int e = 0; e < NEXP; e++) {
        gs[e] = run;
        baseL[e] = run;
        int end = run + cntL[e];
        gep[e] = end;
        for (int r = run; r < end; r += 64) {
          st_e[ns] = e;
          st_row[ns] = r;
          ns++;
        }
        run = (end + 63) & ~63;  // 64-align next group start
      }
      *nstp = ns;
    }
    __syncthreads();
    // Scatter: ballot rank within wave; one atomic per (wave, chunk, expert).
#pragma unroll
    for (int i = 0; i < 16; i++) {
      int t = (wl * 16 + i) * 64 + lane;
      int lv = lab[i];
      int pos = 0;
#pragma unroll
      for (int e = 0; e < NEXP; e++) {
        unsigned long long mk = __ballot(lv == e);
        int c = __popcll(mk);
        if (c) {  // wave-uniform branch
          int src = __ffsll((unsigned long long)mk) - 1;
          int base = 0;
          if (lane == src) base = atomicAdd(&baseL[e], c);
          base = __shfl(base, src, 64);
          if (lv == e) pos = base + __popcll(mk & ((1ull << lane) - 1ull));
        }
      }
      perm[pos] = t;
      iperm[t] = pos;
    }
  } else if (b <= 448) {
    // Weight transpose: slabs 0-8 Wq, 9-17 Wk, 18-26 Wv, 27 Wf; 16 tiles/slab.
    __shared__ short tile[64 * 68];
    int vt = b - 1;
    int slab = vt >> 4;
    const float* src = (slab < 9)    ? Wq + (size_t)slab * 65536
                       : (slab < 18) ? Wk + (size_t)(slab - 9) * 65536
                       : (slab < 27) ? Wv + (size_t)(slab - 18) * 65536
                                     : Wf;
    int xy = vt & 15;
    int d0 = (xy >> 2) * 64, h0 = (xy & 3) * 64;
    int rl = tid >> 4;
    int hh = (tid & 15) * 4;
#pragma unroll
    for (int p = 0; p < 4; p++) {
      int dl = p * 16 + rl;
      float4 v = *(const float4*)(src + (size_t)(d0 + dl) * 256 + h0 + hh);
      s4 o;
      o[0] = f2bf(v.x); o[1] = f2bf(v.y); o[2] = f2bf(v.z); o[3] = f2bf(v.w);
      *(s4*)&tile[dl * 68 + hh] = o;
    }
    __syncthreads();
    int h = tid >> 2, dq = (tid & 3) * 16;
    s8 pa, pb;
#pragma unroll
    for (int i = 0; i < 8; i++) {
      pa[i] = tile[(dq + i) * 68 + h];
      pb[i] = tile[(dq + 8 + i) * 68 + h];
    }
    short* dst = WbT + (size_t)slab * 65536 + (size_t)(h0 + h) * 256 + d0 + dq;
    *(s8*)dst = pa;
    *(s8*)(dst + 8) = pb;
  } else {
    // x -> bf16, token order.
    int tok = (b - 449) * 64 + (tid >> 2);
    int qd = (tid & 3) * 64;
    const float* src = x + (size_t)tok * DIM + qd;
    short* dst = xb + (size_t)tok * DIM + qd;
#pragma unroll
    for (int i = 0; i < 16; i++) {
      float4 v = *(const float4*)(src + i * 4);
      s4 o;
      o[0] = f2bf(v.x); o[1] = f2bf(v.y); o[2] = f2bf(v.z); o[3] = f2bf(v.w);
      *(s4*)(dst + i * 4) = o;
    }
  }
}

// ---------------------------------------------------------------------------
// Kernel 2: MFMA QKV projection. Grid (supertile, colblock 0..3, mtx 0..2);
// wave = 16 grouped rows x 64 cols; A-frags gathered via perm (clamped).
// Epilogue: qg/kg via per-wave LDS transpose -> coalesced 16B stores;
// vgT via contiguous 8B s4 stores.
// ---------------------------------------------------------------------------
__global__ __launch_bounds__(256) void k_proj(
    const short* __restrict__ xb, const short* __restrict__ WbT,
    const float* __restrict__ bq, const float* __restrict__ bk,
    const float* __restrict__ bv, const int* __restrict__ perm,
    const int* __restrict__ gep, const int* __restrict__ st_e,
    const int* __restrict__ st_row, const int* __restrict__ nstp,
    short* __restrict__ qg, short* __restrict__ kg, short* __restrict__ vgT) {
  int b = blockIdx.x;
  if (b >= *nstp) return;
  int gy = blockIdx.y;
  int mtx = blockIdx.z;
  int e = st_e[b];
  int row0 = st_row[b];
  int g1 = gep[e];
  int tid = threadIdx.x, wl = tid >> 6, lane = tid & 63;
  int m = lane & 15, quad = lane >> 4;

  __shared__ short st_s[4][16 * 72];  // per-wave store-transpose buffer

  int row = row0 + wl * 16 + m;
  int pr = perm[(row < g1) ? row : row0];  // clamp padding rows
  const short* Ap = xb + (size_t)pr * DIM + quad * 8;
  const short* Bp = WbT + (size_t)(mtx * 9 + e) * 65536 +
                    (size_t)(gy * 64 + m) * 256 + quad * 8;
  const float* bias = (mtx == 0) ? bq : (mtx == 1) ? bk : bv;

  s8 ac = *(const s8*)Ap;
  s8 bc[4];
#pragma unroll
  for (int t = 0; t < 4; t++) bc[t] = *(const s8*)(Bp + t * 16 * 256);
  f4 acc[4];
#pragma unroll
  for (int t = 0; t < 4; t++) acc[t] = (f4){0.f, 0.f, 0.f, 0.f};
#pragma unroll
  for (int kc = 0; kc < 8; kc++) {
    s8 an = ac;
    s8 bn[4] = {bc[0], bc[1], bc[2], bc[3]};
    if (kc < 7) {
      an = *(const s8*)(Ap + (kc + 1) * 32);
#pragma unroll
      for (int t = 0; t < 4; t++)
        bn[t] = *(const s8*)(Bp + t * 16 * 256 + (kc + 1) * 32);
    }
#pragma unroll
    for (int t = 0; t < 4; t++)
      acc[t] = __builtin_amdgcn_mfma_f32_16x16x32_bf16(ac, bc[t], acc[t], 0, 0, 0);
    ac = an;
#pragma unroll
    for (int t = 0; t < 4; t++) bc[t] = bn[t];
  }

  if (mtx == 2) {
    // vgT[col][grow]: quad owns 4 consecutive grows per col -> 8B s4 stores.
#pragma unroll
    for (int t = 0; t < 4; t++) {
      int col = gy * 64 + t * 16 + m;
      float bs = bias[e * DIM + col];
      s4 o;
#pragma unroll
      for (int r = 0; r < 4; r++) o[r] = f2bf(acc[t][r] + bs);
      *(s4*)&vgT[(size_t)col * VPITCH + row0 + wl * 16 + quad * 4] = o;
    }
  } else {
    // LDS transpose: C-layout -> [row][col] bf16, then coalesced stores.
    short* ws = st_s[wl];
#pragma unroll
    for (int t = 0; t < 4; t++) {
      int col = gy * 64 + t * 16 + m;
      float bs = bias[e * DIM + col];
#pragma unroll
      for (int r = 0; r < 4; r++)
        ws[(quad * 4 + r) * 72 + t * 16 + m] = f2bf(acc[t][r] + bs);
    }
    // same-wave LDS ordering (compiler inserts lgkmcnt)
    int rr = lane >> 2, cg2 = (lane & 3) * 16;
    s8 v0 = *(s8*)&ws[rr * 72 + cg2];
    s8 v1 = *(s8*)&ws[rr * 72 + cg2 + 8];
    short* dst = ((mtx == 1) ? kg : qg) +
                 (size_t)(row0 + wl * 16 + rr) * DIM + gy * 64 + cg2;
    *(s8*)dst = v0;
    *(s8*)(dst + 8) = v1;
  }
}

// ---------------------------------------------------------------------------
// Kernel 3: split-K MFMA flash attention, DOUBLE-BUFFERED K/V staging: one
// barrier per 64-key tile (compute slot cur while prefetched regs store into
// cur^1). Fixed-shift softmax -> additive partials; k_out combines.
// ---------------------------------------------------------------------------
__global__ __launch_bounds__(256) void k_attn(
    const short* __restrict__ qg, const short* __restrict__ kg,
    const short* __restrict__ vgT, const int* __restrict__ gs,
    const int* __restrict__ gep, const int* __restrict__ st_e,
    const int* __restrict__ st_row, const int* __restrict__ nstp,
    float* __restrict__ Op, float* __restrict__ lp) {
  int b = blockIdx.x;
  if (b >= *nstp) return;
  int h = blockIdx.y;
  int sp = blockIdx.z;
  int e = st_e[b];
  int row0 = st_row[b];
  int g0 = gs[e], kend = gep[e];
  int ntiles = (kend - g0 + 63) >> 6;
  int tpc = (ntiles + NSPLIT - 1) / NSPLIT;
  int t0i = sp * tpc;
  int t1i = min(ntiles, t0i + tpc);
  int start = g0 + t0i * 64, end = g0 + t1i * 64;

  int tid = threadIdx.x;
  int wl = tid >> 6, lane = tid & 63;
  int m = lane & 15, quad = lane >> 4;
  int r0 = tid >> 3;
  int c0 = (tid & 7) * 8;

  __shared__ short k_s[2][64 * 72];   // [slot][key][dph]
  __shared__ short v_s[2][64 * 72];   // [slot][dph][key] (transposed)
  __shared__ short p_s[4 * 16 * 72];  // per-wave [qrow][key]

  f4 o_acc[4];
  float l_r[4];
#pragma unroll
  for (int t = 0; t < 4; t++) o_acc[t] = (f4){0.f, 0.f, 0.f, 0.f};
#pragma unroll
  for (int r = 0; r < 4; r++) l_r[r] = 0.f;

  if (start < end) {
    int qrow = row0 + wl * 16 + m;
    if (qrow >= kend) qrow = row0;
    s8 qf0 = *(const s8*)&qg[(size_t)qrow * DIM + h * DPH + quad * 8];
    s8 qf1 = *(const s8*)&qg[(size_t)qrow * DIM + h * DPH + 32 + quad * 8];

    s8 pk0, pk1, pv0, pv1;
#define PREF(JT)                                                              \
  do {                                                                        \
    pk0 = *(const s8*)&kg[(size_t)((JT) + r0) * DIM + h * DPH + c0];          \
    pk1 = *(const s8*)&kg[(size_t)((JT) + r0 + 32) * DIM + h * DPH + c0];     \
    pv0 = *(const s8*)&vgT[(size_t)(h * DPH + r0) * VPITCH + (JT) + c0];      \
    pv1 = *(const s8*)&vgT[(size_t)(h * DPH + r0 + 32) * VPITCH + (JT) + c0]; \
  } while (0)
#define STORE(SL)                            \
  do {                                       \
    *(s8*)&k_s[SL][r0 * 72 + c0] = pk0;      \
    *(s8*)&k_s[SL][(r0 + 32) * 72 + c0] = pk1; \
    *(s8*)&v_s[SL][r0 * 72 + c0] = pv0;      \
    *(s8*)&v_s[SL][(r0 + 32) * 72 + c0] = pv1; \
  } while (0)

    PREF(start);
    STORE(0);
    int cur = 0;
    for (int jt = start; jt < end; jt += 64) {
      int jn = jt + 64;
      bool havenext = jn < end;
      if (havenext) PREF(jn);  // loads land while we compute this tile
      __syncthreads();         // slot-cur stores visible; prev readers done

      f4 s_acc[4];
#pragma unroll
      for (int t = 0; t < 4; t++) s_acc[t] = (f4){0.f, 0.f, 0.f, 0.f};
#pragma unroll
      for (int t = 0; t < 4; t++) {
        s8 kb0 = *(s8*)&k_s[cur][(t * 16 + m) * 72 + quad * 8];
        s8 kb1 = *(s8*)&k_s[cur][(t * 16 + m) * 72 + 32 + quad * 8];
        s_acc[t] = __builtin_amdgcn_mfma_f32_16x16x32_bf16(qf0, kb0, s_acc[t], 0, 0, 0);
        s_acc[t] = __builtin_amdgcn_mfma_f32_16x16x32_bf16(qf1, kb1, s_acc[t], 0, 0, 0);
      }

      // p = exp(s*scale) (bounded scores -> shift-free exact), tail-masked.
#pragma unroll
      for (int t = 0; t < 4; t++) {
        bool ok = (jt + t * 16 + m) < kend;
#pragma unroll
        for (int r = 0; r < 4; r++) {
          float p = ok ? __expf(s_acc[t][r] * SCALE) : 0.f;
          l_r[r] += p;
          p_s[(wl * 16 + quad * 4 + r) * 72 + t * 16 + m] = f2bf(p);
        }
      }

#pragma unroll
      for (int kk = 0; kk < 2; kk++) {
        s8 pa = *(s8*)&p_s[(wl * 16 + m) * 72 + kk * 32 + quad * 8];
#pragma unroll
        for (int t = 0; t < 4; t++) {
          s8 vb = *(s8*)&v_s[cur][(t * 16 + m) * 72 + kk * 32 + quad * 8];
          o_acc[t] = __builtin_amdgcn_mfma_f32_16x16x32_bf16(pa, vb, o_acc[t], 0, 0, 0);
        }
      }

      if (havenext) STORE(cur ^ 1);  // next tile into the other slot
      cur ^= 1;
    }
#undef PREF
#undef STORE
  }

  // Epilogue: write UNNORMALIZED partial O (f32, coalesced 64B segments) +
  // partial l. Empty chunks write zeros so k_out never reads poisoned ws.
  float* Ob = Op + (size_t)sp * GPAD * DIM;
#pragma unroll
  for (int r = 0; r < 4; r++) {
    float lt = l_r[r];
#pragma unroll
    for (int o = 8; o > 0; o >>= 1) lt += __shfl_xor(lt, o, 64);
    int grow = row0 + wl * 16 + quad * 4 + r;
    if (m == 0) lp[(size_t)(sp * NHEAD + h) * GPAD + grow] = lt;
#pragma unroll
    for (int t = 0; t < 4; t++)
      Ob[(size_t)grow * DIM + h * DPH + t * 16 + m] = o_acc[t][r];
  }
}

// ---------------------------------------------------------------------------
// Kernel 4: combine splits + out-proj + LayerNorm. Block = 16 tokens (token
// order). Each thread sums NSPLIT partials for its A-frag row, divides by
// summed l, converts to bf16 frags, then MFMA Wf GEMM + residual + LN.
// ---------------------------------------------------------------------------
__global__ __launch_bounds__(256) void k_out(
    const float* __restrict__ Op, const float* __restrict__ lp,
    const int* __restrict__ iperm, const short* __restrict__ WbT,
    const float* __restrict__ x, const float* __restrict__ bfv,
    const float* __restrict__ gamma, const float* __restrict__ beta,
    float* __restrict__ out) {
  int t0 = blockIdx.x * 16;
  int tid = threadIdx.x, wl = tid >> 6, lane = tid & 63;
  int m = lane & 15, quad = lane >> 4;
  __shared__ float h_s[16 * 260];

  int grow = iperm[t0 + m];
  float inv[NHEAD];
#pragma unroll
  for (int h = 0; h < NHEAD; h++) {
    float s = 0.f;
#pragma unroll
    for (int sp = 0; sp < NSPLIT; sp++)
      s += lp[(size_t)(sp * NHEAD + h) * GPAD + grow];
    inv[h] = 1.f / s;
  }

  s8 af[8];
#pragma unroll
  for (int kc = 0; kc < 8; kc++) {
    f4 s0 = (f4){0.f, 0.f, 0.f, 0.f}, s1 = (f4){0.f, 0.f, 0.f, 0.f};
#pragma unroll
    for (int sp = 0; sp < NSPLIT; sp++) {
      const float* p =
          Op + ((size_t)sp * GPAD + grow) * DIM + kc * 32 + quad * 8;
      s0 += *(const f4*)p;
      s1 += *(const f4*)(p + 4);
    }
    float iv = inv[kc >> 1];
#pragma unroll
    for (int j = 0; j < 4; j++) {
      af[kc][j] = f2bf(s0[j] * iv);
      af[kc][4 + j] = f2bf(s1[j] * iv);
    }
  }

  const short* Bp =
      WbT + (size_t)27 * 65536 + (size_t)(wl * 64 + m) * 256 + quad * 8;
  f4 acc[4];
#pragma unroll
  for (int t = 0; t < 4; t++) acc[t] = (f4){0.f, 0.f, 0.f, 0.f};
#pragma unroll
  for (int kc = 0; kc < 8; kc++)
#pragma unroll
    for (int t = 0; t < 4; t++) {
      s8 wb = *(const s8*)(Bp + t * 16 * 256 + kc * 32);
      acc[t] = __builtin_amdgcn_mfma_f32_16x16x32_bf16(af[kc], wb, acc[t], 0, 0, 0);
    }

#pragma unroll
  for (int t = 0; t < 4; t++) {
    int col = wl * 64 + t * 16 + m;
    float bs = bfv[col];
#pragma unroll
    for (int r = 0; r < 4; r++) h_s[(quad * 4 + r) * 260 + col] = acc[t][r] + bs;
  }
  __syncthreads();

#pragma unroll
  for (int rr = 0; rr < 4; rr++) {
    int row = wl * 4 + rr;
    float hv[4];
#pragma unroll
    for (int k2 = 0; k2 < 4; k2++)
      hv[k2] = h_s[row * 260 + lane + 64 * k2] +
               x[(size_t)(t0 + row) * DIM + lane + 64 * k2];
    float mean = wave_sum(hv[0] + hv[1] + hv[2] + hv[3]) * (1.f / 256.f);
    float sq = 0.f;
#pragma unroll
    for (int k2 = 0; k2 < 4; k2++) {
      float dd = hv[k2] - mean;
      sq += dd * dd;
    }
    float rstd = rsqrtf(wave_sum(sq) * (1.f / 256.f) + 1e-5f);
#pragma unroll
    for (int k2 = 0; k2 < 4; k2++) {
      int c = lane + 64 * k2;
      out[(size_t)(t0 + row) * DIM + c] =
          gamma[c] * ((hv[k2] - mean) * rstd) + beta[c];
    }
  }
}

// ---------------------------------------------------------------------------
extern "C" void kernel_launch(void* const* d_in, const int* in_sizes, int n_in,
                              void* d_out, int out_size, void* d_ws,
                              size_t ws_size, hipStream_t stream) {
  const float* x = (const float*)d_in[0];
  const int* label = (const int*)d_in[1];
  const float* Wq = (const float*)d_in[2];
  const float* bq = (const float*)d_in[3];
  const float* Wk = (const float*)d_in[4];
  const float* bk = (const float*)d_in[5];
  const float* Wv = (const float*)d_in[6];
  const float* bv = (const float*)d_in[7];
  const float* Wf = (const float*)d_in[8];
  const float* bfv = (const float*)d_in[9];
  const float* gamma = (const float*)d_in[10];
  const float* beta = (const float*)d_in[11];
  float* out = (float*)d_out;

  // Workspace (~25 MB of 256 MB).
  int* perm = (int*)d_ws;        // 4800 slot
  int* iperm = perm + 4800;      // 4096
  int* gs = iperm + 4096;        // 16
  int* gep = gs + 16;            // 16
  int* st_e = gep + 16;          // 128
  int* st_row = st_e + 128;      // 128
  int* nstp = st_row + 128;      // 8
  short* qg = (short*)((char*)d_ws + 65536);
  short* kg = qg + (size_t)GPAD * DIM;
  short* vgT = kg + (size_t)GPAD * DIM;
  short* WbT = vgT + (size_t)DIM * VPITCH;
  short* xb = WbT + (size_t)28 * 65536;
  float* Op = (float*)(xb + (size_t)N_TOK * DIM);   // [NSPLIT][GPAD][256] f32
  float* lp = Op + (size_t)NSPLIT * GPAD * DIM;     // [NSPLIT][4][GPAD] f32

  hipLaunchKernelGGL(k_prep, dim3(513), dim3(256), 0, stream, x, label, Wq, Wk,
                     Wv, Wf, perm, iperm, gs, gep, st_e, st_row, nstp, WbT, xb);
  hipLaunchKernelGGL(k_proj, dim3(MAXST, 4, 3), dim3(256), 0, stream, xb, WbT,
                     bq, bk, bv, perm, gep, st_e, st_row, nstp, qg, kg, vgT);
  hipLaunchKernelGGL(k_attn, dim3(MAXST, NHEAD, NSPLIT), dim3(256), 0, stream,
                     qg, kg, vgT, gs, gep, st_e, st_row, nstp, Op, lp);
  hipLaunchKernelGGL(k_out, dim3(N_TOK / 16), dim3(256), 0, stream, Op, lp,
                     iperm, WbT, x, bfv, gamma, beta, out);
}

// Round 10
// 139.255 us; speedup vs baseline: 1.1831x; 1.1831x over previous
//
#include <hip/hip_runtime.h>
#include <math.h>

#define N_TOK 4096
#define DIM 256
#define NHEAD 4
#define DPH 64
#define NEXP 9
#define SCALE 0.25f
#define MAXST 80    // 64-row supertiles: <= 64 + 9
#define GPAD 4736   // 64-aligned grouped rows upper bound
#define VPITCH 4736
#define NSPLIT 2    // key-range splits per (supertile, head)

typedef short s8 __attribute__((ext_vector_type(8)));
typedef short s4 __attribute__((ext_vector_type(4)));
typedef float f4 __attribute__((ext_vector_type(4)));

static __device__ __forceinline__ short f2bf(float f) {
  union { float f; unsigned u; } v;
  v.f = f;
  unsigned r = (v.u + 0x7FFFu + ((v.u >> 16) & 1u)) >> 16;
  return (short)r;
}

static __device__ __forceinline__ float wave_sum(float v) {
#pragma unroll
  for (int o = 32; o > 0; o >>= 1) v += __shfl_xor(v, o, 64);
  return v;
}

// ---------------------------------------------------------------------------
// Kernel 1: prep. Block 0: bucket tokens — ATOMIC-FREE build: per-wave ballot
// histogram (wave-uniform register counts), LDS cross-wave prefix, then
// deterministic rank scatter (base + running + popcount(below)). No LDS
// atomics, no ds_bpermute chains (R9's straggler). Blocks 1..448: W fp32
// [d][h] -> WbT bf16 [slab][h][d]. Blocks 449..512: x -> bf16 cast.
// ---------------------------------------------------------------------------
__global__ __launch_bounds__(256) void k_prep(
    const float* __restrict__ x, const int* __restrict__ label,
    const float* __restrict__ Wq, const float* __restrict__ Wk,
    const float* __restrict__ Wv, const float* __restrict__ Wf,
    int* __restrict__ perm, int* __restrict__ iperm, int* __restrict__ gs,
    int* __restrict__ gep, int* __restrict__ st_e, int* __restrict__ st_row,
    int* __restrict__ nstp, short* __restrict__ WbT, short* __restrict__ xb) {
  int b = blockIdx.x;
  int tid = threadIdx.x;
  if (b == 0) {
    __shared__ int cnt_s[4][NEXP];  // per-wave counts
    __shared__ int gsh[NEXP];       // group starts (LDS copy)
    int wl = tid >> 6, lane = tid & 63;
    int lab[16];
#pragma unroll
    for (int i = 0; i < 16; i++) lab[i] = label[wl * 1024 + i * 64 + lane];

    // Count: ballot popcount, accumulated in wave-uniform registers.
    int cw[NEXP];
#pragma unroll
    for (int e = 0; e < NEXP; e++) cw[e] = 0;
#pragma unroll
    for (int i = 0; i < 16; i++)
#pragma unroll
      for (int e = 0; e < NEXP; e++)
        cw[e] += __popcll(__ballot(lab[i] == e));
    if (lane == 0)
#pragma unroll
      for (int e = 0; e < NEXP; e++) cnt_s[wl][e] = cw[e];
    __syncthreads();

    if (tid == 0) {
      int run = 0, ns = 0;
      for (int e = 0; e < NEXP; e++) {
        int tot = cnt_s[0][e] + cnt_s[1][e] + cnt_s[2][e] + cnt_s[3][e];
        gs[e] = run;
        gsh[e] = run;
        int end = run + tot;
        gep[e] = end;
        for (int r = run; r < end; r += 64) {
          st_e[ns] = e;
          st_row[ns] = r;
          ns++;
        }
        run = (end + 63) & ~63;  // 64-align next group start
      }
      *nstp = ns;
    }
    __syncthreads();

    // Per-wave base = group start + counts of lower waves.
    int baseW[NEXP];
#pragma unroll
    for (int e = 0; e < NEXP; e++) {
      int bse = gsh[e];
      for (int w = 0; w < 4; w++)
        if (w < wl) bse += cnt_s[w][e];
      baseW[e] = bse;
    }
    // Scatter: deterministic rank, zero atomics.
    int run2[NEXP];
#pragma unroll
    for (int e = 0; e < NEXP; e++) run2[e] = 0;
#pragma unroll
    for (int i = 0; i < 16; i++) {
      int t = wl * 1024 + i * 64 + lane;
      int lv = lab[i];
      unsigned long long below = (1ull << lane) - 1ull;
      int pos = 0;
#pragma unroll
      for (int e = 0; e < NEXP; e++) {
        unsigned long long mk = __ballot(lv == e);
        if (lv == e) pos = baseW[e] + run2[e] + __popcll(mk & below);
        run2[e] += __popcll(mk);
      }
      perm[pos] = t;
      iperm[t] = pos;
    }
  } else if (b <= 448) {
    // Weight transpose: slabs 0-8 Wq, 9-17 Wk, 18-26 Wv, 27 Wf; 16 tiles/slab.
    __shared__ short tile[64 * 68];
    int vt = b - 1;
    int slab = vt >> 4;
    const float* src = (slab < 9)    ? Wq + (size_t)slab * 65536
                       : (slab < 18) ? Wk + (size_t)(slab - 9) * 65536
                       : (slab < 27) ? Wv + (size_t)(slab - 18) * 65536
                                     : Wf;
    int xy = vt & 15;
    int d0 = (xy >> 2) * 64, h0 = (xy & 3) * 64;
    int rl = tid >> 4;
    int hh = (tid & 15) * 4;
#pragma unroll
    for (int p = 0; p < 4; p++) {
      int dl = p * 16 + rl;
      float4 v = *(const float4*)(src + (size_t)(d0 + dl) * 256 + h0 + hh);
      s4 o;
      o[0] = f2bf(v.x); o[1] = f2bf(v.y); o[2] = f2bf(v.z); o[3] = f2bf(v.w);
      *(s4*)&tile[dl * 68 + hh] = o;
    }
    __syncthreads();
    int h = tid >> 2, dq = (tid & 3) * 16;
    s8 pa, pb;
#pragma unroll
    for (int i = 0; i < 8; i++) {
      pa[i] = tile[(dq + i) * 68 + h];
      pb[i] = tile[(dq + 8 + i) * 68 + h];
    }
    short* dst = WbT + (size_t)slab * 65536 + (size_t)(h0 + h) * 256 + d0 + dq;
    *(s8*)dst = pa;
    *(s8*)(dst + 8) = pb;
  } else {
    // x -> bf16, token order.
    int tok = (b - 449) * 64 + (tid >> 2);
    int qd = (tid & 3) * 64;
    const float* src = x + (size_t)tok * DIM + qd;
    short* dst = xb + (size_t)tok * DIM + qd;
#pragma unroll
    for (int i = 0; i < 16; i++) {
      float4 v = *(const float4*)(src + i * 4);
      s4 o;
      o[0] = f2bf(v.x); o[1] = f2bf(v.y); o[2] = f2bf(v.z); o[3] = f2bf(v.w);
      *(s4*)(dst + i * 4) = o;
    }
  }
}

// ---------------------------------------------------------------------------
// Kernel 2: MFMA QKV projection. Grid (supertile, colblock 0..3, mtx 0..2);
// wave = 16 grouped rows x 64 cols; A-frags gathered via perm (clamped).
// Epilogue: qg/kg via per-wave LDS transpose -> coalesced 16B stores;
// vgT via contiguous 8B s4 stores.
// ---------------------------------------------------------------------------
__global__ __launch_bounds__(256) void k_proj(
    const short* __restrict__ xb, const short* __restrict__ WbT,
    const float* __restrict__ bq, const float* __restrict__ bk,
    const float* __restrict__ bv, const int* __restrict__ perm,
    const int* __restrict__ gep, const int* __restrict__ st_e,
    const int* __restrict__ st_row, const int* __restrict__ nstp,
    short* __restrict__ qg, short* __restrict__ kg, short* __restrict__ vgT) {
  int b = blockIdx.x;
  if (b >= *nstp) return;
  int gy = blockIdx.y;
  int mtx = blockIdx.z;
  int e = st_e[b];
  int row0 = st_row[b];
  int g1 = gep[e];
  int tid = threadIdx.x, wl = tid >> 6, lane = tid & 63;
  int m = lane & 15, quad = lane >> 4;

  __shared__ short st_s[4][16 * 72];  // per-wave store-transpose buffer

  int row = row0 + wl * 16 + m;
  int pr = perm[(row < g1) ? row : row0];  // clamp padding rows
  const short* Ap = xb + (size_t)pr * DIM + quad * 8;
  const short* Bp = WbT + (size_t)(mtx * 9 + e) * 65536 +
                    (size_t)(gy * 64 + m) * 256 + quad * 8;
  const float* bias = (mtx == 0) ? bq : (mtx == 1) ? bk : bv;

  s8 ac = *(const s8*)Ap;
  s8 bc[4];
#pragma unroll
  for (int t = 0; t < 4; t++) bc[t] = *(const s8*)(Bp + t * 16 * 256);
  f4 acc[4];
#pragma unroll
  for (int t = 0; t < 4; t++) acc[t] = (f4){0.f, 0.f, 0.f, 0.f};
#pragma unroll
  for (int kc = 0; kc < 8; kc++) {
    s8 an = ac;
    s8 bn[4] = {bc[0], bc[1], bc[2], bc[3]};
    if (kc < 7) {
      an = *(const s8*)(Ap + (kc + 1) * 32);
#pragma unroll
      for (int t = 0; t < 4; t++)
        bn[t] = *(const s8*)(Bp + t * 16 * 256 + (kc + 1) * 32);
    }
#pragma unroll
    for (int t = 0; t < 4; t++)
      acc[t] = __builtin_amdgcn_mfma_f32_16x16x32_bf16(ac, bc[t], acc[t], 0, 0, 0);
    ac = an;
#pragma unroll
    for (int t = 0; t < 4; t++) bc[t] = bn[t];
  }

  if (mtx == 2) {
    // vgT[col][grow]: quad owns 4 consecutive grows per col -> 8B s4 stores.
#pragma unroll
    for (int t = 0; t < 4; t++) {
      int col = gy * 64 + t * 16 + m;
      float bs = bias[e * DIM + col];
      s4 o;
#pragma unroll
      for (int r = 0; r < 4; r++) o[r] = f2bf(acc[t][r] + bs);
      *(s4*)&vgT[(size_t)col * VPITCH + row0 + wl * 16 + quad * 4] = o;
    }
  } else {
    // LDS transpose: C-layout -> [row][col] bf16, then coalesced stores.
    short* ws = st_s[wl];
#pragma unroll
    for (int t = 0; t < 4; t++) {
      int col = gy * 64 + t * 16 + m;
      float bs = bias[e * DIM + col];
#pragma unroll
      for (int r = 0; r < 4; r++)
        ws[(quad * 4 + r) * 72 + t * 16 + m] = f2bf(acc[t][r] + bs);
    }
    // same-wave LDS ordering (compiler inserts lgkmcnt)
    int rr = lane >> 2, cg2 = (lane & 3) * 16;
    s8 v0 = *(s8*)&ws[rr * 72 + cg2];
    s8 v1 = *(s8*)&ws[rr * 72 + cg2 + 8];
    short* dst = ((mtx == 1) ? kg : qg) +
                 (size_t)(row0 + wl * 16 + rr) * DIM + gy * 64 + cg2;
    *(s8*)dst = v0;
    *(s8*)(dst + 8) = v1;
  }
}

// ---------------------------------------------------------------------------
// Kernel 3: split-K MFMA flash attention (single-buffered K/V staging — R8
// config; dbuf measured neutral and costs occupancy). Fixed-shift softmax ->
// additive partials; k_out combines.
// ---------------------------------------------------------------------------
__global__ __launch_bounds__(256) void k_attn(
    const short* __restrict__ qg, const short* __restrict__ kg,
    const short* __restrict__ vgT, const int* __restrict__ gs,
    const int* __restrict__ gep, const int* __restrict__ st_e,
    const int* __restrict__ st_row, const int* __restrict__ nstp,
    float* __restrict__ Op, float* __restrict__ lp) {
  int b = blockIdx.x;
  if (b >= *nstp) return;
  int h = blockIdx.y;
  int sp = blockIdx.z;
  int e = st_e[b];
  int row0 = st_row[b];
  int g0 = gs[e], kend = gep[e];
  int ntiles = (kend - g0 + 63) >> 6;
  int tpc = (ntiles + NSPLIT - 1) / NSPLIT;
  int t0i = sp * tpc;
  int t1i = min(ntiles, t0i + tpc);
  int start = g0 + t0i * 64, end = g0 + t1i * 64;

  int tid = threadIdx.x;
  int wl = tid >> 6, lane = tid & 63;
  int m = lane & 15, quad = lane >> 4;
  int r0 = tid >> 3;
  int c0 = (tid & 7) * 8;

  __shared__ short k_s[64 * 72];      // [key][dph]
  __shared__ short v_s[64 * 72];      // [dph][key] (transposed)
  __shared__ short p_s[4 * 16 * 72];  // per-wave [qrow][key]

  f4 o_acc[4];
  float l_r[4];
#pragma unroll
  for (int t = 0; t < 4; t++) o_acc[t] = (f4){0.f, 0.f, 0.f, 0.f};
#pragma unroll
  for (int r = 0; r < 4; r++) l_r[r] = 0.f;

  if (start < end) {
    int qrow = row0 + wl * 16 + m;
    if (qrow >= kend) qrow = row0;
    s8 qf0 = *(const s8*)&qg[(size_t)qrow * DIM + h * DPH + quad * 8];
    s8 qf1 = *(const s8*)&qg[(size_t)qrow * DIM + h * DPH + 32 + quad * 8];

    s8 pk0, pk1, pv0, pv1;
#define PREF(JT)                                                              \
  do {                                                                        \
    pk0 = *(const s8*)&kg[(size_t)((JT) + r0) * DIM + h * DPH + c0];          \
    pk1 = *(const s8*)&kg[(size_t)((JT) + r0 + 32) * DIM + h * DPH + c0];     \
    pv0 = *(const s8*)&vgT[(size_t)(h * DPH + r0) * VPITCH + (JT) + c0];      \
    pv1 = *(const s8*)&vgT[(size_t)(h * DPH + r0 + 32) * VPITCH + (JT) + c0]; \
  } while (0)

    PREF(start);
    for (int jt = start; jt < end; jt += 64) {
      __syncthreads();  // prev tile's LDS readers done
      *(s8*)&k_s[r0 * 72 + c0] = pk0;
      *(s8*)&k_s[(r0 + 32) * 72 + c0] = pk1;
      *(s8*)&v_s[r0 * 72 + c0] = pv0;
      *(s8*)&v_s[(r0 + 32) * 72 + c0] = pv1;
      int jn = jt + 64;
      if (jn < end) PREF(jn);  // overlap next tile's loads with compute
      __syncthreads();

      f4 s_acc[4];
#pragma unroll
      for (int t = 0; t < 4; t++) s_acc[t] = (f4){0.f, 0.f, 0.f, 0.f};
#pragma unroll
      for (int t = 0; t < 4; t++) {
        s8 kb0 = *(s8*)&k_s[(t * 16 + m) * 72 + quad * 8];
        s8 kb1 = *(s8*)&k_s[(t * 16 + m) * 72 + 32 + quad * 8];
        s_acc[t] = __builtin_amdgcn_mfma_f32_16x16x32_bf16(qf0, kb0, s_acc[t], 0, 0, 0);
        s_acc[t] = __builtin_amdgcn_mfma_f32_16x16x32_bf16(qf1, kb1, s_acc[t], 0, 0, 0);
      }

      // p = exp(s*scale) (bounded scores -> shift-free exact), tail-masked.
#pragma unroll
      for (int t = 0; t < 4; t++) {
        bool ok = (jt + t * 16 + m) < kend;
#pragma unroll
        for (int r = 0; r < 4; r++) {
          float p = ok ? __expf(s_acc[t][r] * SCALE) : 0.f;
          l_r[r] += p;
          p_s[(wl * 16 + quad * 4 + r) * 72 + t * 16 + m] = f2bf(p);
        }
      }

#pragma unroll
      for (int kk = 0; kk < 2; kk++) {
        s8 pa = *(s8*)&p_s[(wl * 16 + m) * 72 + kk * 32 + quad * 8];
#pragma unroll
        for (int t = 0; t < 4; t++) {
          s8 vb = *(s8*)&v_s[(t * 16 + m) * 72 + kk * 32 + quad * 8];
          o_acc[t] = __builtin_amdgcn_mfma_f32_16x16x32_bf16(pa, vb, o_acc[t], 0, 0, 0);
        }
      }
    }
#undef PREF
  }

  // Epilogue: write UNNORMALIZED partial O (f32, coalesced 64B segments) +
  // partial l. Empty chunks write zeros so k_out never reads poisoned ws.
  float* Ob = Op + (size_t)sp * GPAD * DIM;
#pragma unroll
  for (int r = 0; r < 4; r++) {
    float lt = l_r[r];
#pragma unroll
    for (int o = 8; o > 0; o >>= 1) lt += __shfl_xor(lt, o, 64);
    int grow = row0 + wl * 16 + quad * 4 + r;
    if (m == 0) lp[(size_t)(sp * NHEAD + h) * GPAD + grow] = lt;
#pragma unroll
    for (int t = 0; t < 4; t++)
      Ob[(size_t)grow * DIM + h * DPH + t * 16 + m] = o_acc[t][r];
  }
}

// ---------------------------------------------------------------------------
// Kernel 4: combine splits + out-proj + LayerNorm. Block = 16 tokens (token
// order). Each thread sums NSPLIT partials for its A-frag row, divides by
// summed l, converts to bf16 frags, then MFMA Wf GEMM + residual + LN.
// ---------------------------------------------------------------------------
__global__ __launch_bounds__(256) void k_out(
    const float* __restrict__ Op, const float* __restrict__ lp,
    const int* __restrict__ iperm, const short* __restrict__ WbT,
    const float* __restrict__ x, const float* __restrict__ bfv,
    const float* __restrict__ gamma, const float* __restrict__ beta,
    float* __restrict__ out) {
  int t0 = blockIdx.x * 16;
  int tid = threadIdx.x, wl = tid >> 6, lane = tid & 63;
  int m = lane & 15, quad = lane >> 4;
  __shared__ float h_s[16 * 260];

  int grow = iperm[t0 + m];
  float inv[NHEAD];
#pragma unroll
  for (int h = 0; h < NHEAD; h++) {
    float s = 0.f;
#pragma unroll
    for (int sp = 0; sp < NSPLIT; sp++)
      s += lp[(size_t)(sp * NHEAD + h) * GPAD + grow];
    inv[h] = 1.f / s;
  }

  s8 af[8];
#pragma unroll
  for (int kc = 0; kc < 8; kc++) {
    f4 s0 = (f4){0.f, 0.f, 0.f, 0.f}, s1 = (f4){0.f, 0.f, 0.f, 0.f};
#pragma unroll
    for (int sp = 0; sp < NSPLIT; sp++) {
      const float* p =
          Op + ((size_t)sp * GPAD + grow) * DIM + kc * 32 + quad * 8;
      s0 += *(const f4*)p;
      s1 += *(const f4*)(p + 4);
    }
    float iv = inv[kc >> 1];
#pragma unroll
    for (int j = 0; j < 4; j++) {
      af[kc][j] = f2bf(s0[j] * iv);
      af[kc][4 + j] = f2bf(s1[j] * iv);
    }
  }

  const short* Bp =
      WbT + (size_t)27 * 65536 + (size_t)(wl * 64 + m) * 256 + quad * 8;
  f4 acc[4];
#pragma unroll
  for (int t = 0; t < 4; t++) acc[t] = (f4){0.f, 0.f, 0.f, 0.f};
#pragma unroll
  for (int kc = 0; kc < 8; kc++)
#pragma unroll
    for (int t = 0; t < 4; t++) {
      s8 wb = *(const s8*)(Bp + t * 16 * 256 + kc * 32);
      acc[t] = __builtin_amdgcn_mfma_f32_16x16x32_bf16(af[kc], wb, acc[t], 0, 0, 0);
    }

#pragma unroll
  for (int t = 0; t < 4; t++) {
    int col = wl * 64 + t * 16 + m;
    float bs = bfv[col];
#pragma unroll
    for (int r = 0; r < 4; r++) h_s[(quad * 4 + r) * 260 + col] = acc[t][r] + bs;
  }
  __syncthreads();

#pragma unroll
  for (int rr = 0; rr < 4; rr++) {
    int row = wl * 4 + rr;
    float hv[4];
#pragma unroll
    for (int k2 = 0; k2 < 4; k2++)
      hv[k2] = h_s[row * 260 + lane + 64 * k2] +
               x[(size_t)(t0 + row) * DIM + lane + 64 * k2];
    float mean = wave_sum(hv[0] + hv[1] + hv[2] + hv[3]) * (1.f / 256.f);
    float sq = 0.f;
#pragma unroll
    for (int k2 = 0; k2 < 4; k2++) {
      float dd = hv[k2] - mean;
      sq += dd * dd;
    }
    float rstd = rsqrtf(wave_sum(sq) * (1.f / 256.f) + 1e-5f);
#pragma unroll
    for (int k2 = 0; k2 < 4; k2++) {
      int c = lane + 64 * k2;
      out[(size_t)(t0 + row) * DIM + c] =
          gamma[c] * ((hv[k2] - mean) * rstd) + beta[c];
    }
  }
}

// ---------------------------------------------------------------------------
extern "C" void kernel_launch(void* const* d_in, const int* in_sizes, int n_in,
                              void* d_out, int out_size, void* d_ws,
                              size_t ws_size, hipStream_t stream) {
  const float* x = (const float*)d_in[0];
  const int* label = (const int*)d_in[1];
  const float* Wq = (const float*)d_in[2];
  const float* bq = (const float*)d_in[3];
  const float* Wk = (const float*)d_in[4];
  const float* bk = (const float*)d_in[5];
  const float* Wv = (const float*)d_in[6];
  const float* bv = (const float*)d_in[7];
  const float* Wf = (const float*)d_in[8];
  const float* bfv = (const float*)d_in[9];
  const float* gamma = (const float*)d_in[10];
  const float* beta = (const float*)d_in[11];
  float* out = (float*)d_out;

  // Workspace (~25 MB of 256 MB).
  int* perm = (int*)d_ws;        // 4800 slot
  int* iperm = perm + 4800;      // 4096
  int* gs = iperm + 4096;        // 16
  int* gep = gs + 16;            // 16
  int* st_e = gep + 16;          // 128
  int* st_row = st_e + 128;      // 128
  int* nstp = st_row + 128;      // 8
  short* qg = (short*)((char*)d_ws + 65536);
  short* kg = qg + (size_t)GPAD * DIM;
  short* vgT = kg + (size_t)GPAD * DIM;
  short* WbT = vgT + (size_t)DIM * VPITCH;
  short* xb = WbT + (size_t)28 * 65536;
  float* Op = (float*)(xb + (size_t)N_TOK * DIM);   // [NSPLIT][GPAD][256] f32
  float* lp = Op + (size_t)NSPLIT * GPAD * DIM;     // [NSPLIT][4][GPAD] f32

  hipLaunchKernelGGL(k_prep, dim3(513), dim3(256), 0, stream, x, label, Wq, Wk,
                     Wv, Wf, perm, iperm, gs, gep, st_e, st_row, nstp, WbT, xb);
  hipLaunchKernelGGL(k_proj, dim3(MAXST, 4, 3), dim3(256), 0, stream, xb, WbT,
                     bq, bk, bv, perm, gep, st_e, st_row, nstp, qg, kg, vgT);
  hipLaunchKernelGGL(k_attn, dim3(MAXST, NHEAD, NSPLIT), dim3(256), 0, stream,
                     qg, kg, vgT, gs, gep, st_e, st_row, nstp, Op, lp);
  hipLaunchKernelGGL(k_out, dim3(N_TOK / 16), dim3(256), 0, stream, Op, lp,
                     iperm, WbT, x, bfv, gamma, beta, out);
}